// Round 2
// baseline (45.163 us; speedup 1.0000x reference)
//
#include <hip/hip_runtime.h>

#define HH 512
#define WW 512
#define NB 8
constexpr int   NPIX = HH * WW;              // 262144 pixels per batch
constexpr int   FH   = (HH - 1) * (WW - 1);  // 261121 lower faces per batch
constexpr int   NF   = 2 * FH;               // 522242 faces per batch
constexpr float EPS       = 0.04f;
constexpr float DEPTH_MIN = 0.1f;
constexpr float EDGE_MAX  = 0.1f;

// ---------------------------------------------------------------------------
// Kernel 1: per-pixel unprojection, 4 pixels per thread, all float4 traffic.
//   v = c2w_ext · [ c2w_int · (x*z, y*z, z), 1 ]
//   a = attributes with edge extension on last row / last col / corner.
// v/a store base = (b*NPIX + pix0)*3 floats; pix0 % 4 == 0 -> 48B aligned.
// ---------------------------------------------------------------------------
__global__ void __launch_bounds__(256)
unproject_kernel(const float* __restrict__ attr_d,
                 const float* __restrict__ c2w_int,
                 const float* __restrict__ c2w_ext,
                 float* __restrict__ out_v,
                 float* __restrict__ out_a) {
    int idx  = blockIdx.x * 256 + threadIdx.x;   // one thread = 4 pixels
    int b    = idx >> 16;                        // NPIX/4 = 65536 groups/batch
    int rem  = idx & 65535;
    int pix0 = rem << 2;
    int h    = pix0 >> 9;                        // W = 512
    int w0   = pix0 & 511;

    const float* base = attr_d + (size_t)b * 4 * NPIX;  // planar (C,H,W)

    float4 z4 = *(const float4*)(base + 3 * NPIX + pix0);
    float z[4] = {z4.x, z4.y, z4.z, z4.w};

    // attributes with boundary extension; the three update regions read
    // only original (un-updated) values (verified against ref update order)
    float a[3][4];
#pragma unroll
    for (int c = 0; c < 3; ++c) {
        const float* pc = base + c * NPIX;
        float4 ac = *(const float4*)(pc + pix0);
        a[c][0] = ac.x; a[c][1] = ac.y; a[c][2] = ac.z; a[c][3] = ac.w;
        if (h == HH - 1) {
            // last row: neighbor is row above (same col); corner uses diag
            float4 uc = *(const float4*)(pc + pix0 - WW);
            float u[4] = {uc.x, uc.y, uc.z, uc.w};
#pragma unroll
            for (int j = 0; j < 4; ++j) {
                float nb = (w0 + j == WW - 1) ? u[2] : u[j];   // diag for corner
                a[c][j] += (a[c][j] - nb) * EPS;
            }
        } else if (w0 == WW - 4) {
            // last col (not last row): neighbor is lane-local element 2
            a[c][3] += (a[c][3] - a[c][2]) * EPS;
        }
    }

    const float* K = c2w_int + b * 9;   // 3x3
    const float* E = c2w_ext + b * 12;  // 3x4
    float K0=K[0],K1=K[1],K2=K[2],K3=K[3],K4=K[4],K5=K[5],K6=K[6],K7=K[7],K8=K[8];
    float E0=E[0],E1=E[1],E2=E[2],E3=E[3],E4=E[4],E5=E[5],
          E6=E[6],E7=E[7],E8=E[8],E9=E[9],E10=E[10],E11=E[11];

    float yc = (h == HH - 1) ? ((float)HH - 0.5f + EPS) : ((float)h + 0.5f);

    float vout[12], aout[12];
#pragma unroll
    for (int j = 0; j < 4; ++j) {
        int w = w0 + j;
        float xc = (w == WW - 1) ? ((float)WW - 0.5f + EPS) : ((float)w + 0.5f);
        float p0 = xc * z[j], p1 = yc * z[j], p2 = z[j];
        float vi0 = K0 * p0 + K1 * p1 + K2 * p2;
        float vi1 = K3 * p0 + K4 * p1 + K5 * p2;
        float vi2 = K6 * p0 + K7 * p1 + K8 * p2;
        vout[j*3+0] = E0 * vi0 + E1 * vi1 + E2  * vi2 + E3;
        vout[j*3+1] = E4 * vi0 + E5 * vi1 + E6  * vi2 + E7;
        vout[j*3+2] = E8 * vi0 + E9 * vi1 + E10 * vi2 + E11;
        aout[j*3+0] = a[0][j];
        aout[j*3+1] = a[1][j];
        aout[j*3+2] = a[2][j];
    }

    size_t vo = ((size_t)b * NPIX + pix0) * 3;   // 48B aligned
    float4* vp = (float4*)(out_v + vo);
    vp[0] = make_float4(vout[0], vout[1], vout[2],  vout[3]);
    vp[1] = make_float4(vout[4], vout[5], vout[6],  vout[7]);
    vp[2] = make_float4(vout[8], vout[9], vout[10], vout[11]);
    float4* ap = (float4*)(out_a + vo);
    ap[0] = make_float4(aout[0], aout[1], aout[2],  aout[3]);
    ap[1] = make_float4(aout[4], aout[5], aout[6],  aout[7]);
    ap[2] = make_float4(aout[8], aout[9], aout[10], aout[11]);
}

__device__ __forceinline__ float edge_len3(float ax, float ay, float az,
                                           float bx, float by, float bz) {
    float dx = ax - bx, dy = ay - by, dz = az - bz;
    return sqrtf(dx * dx + dy * dy + dz * dz);
}

// cooperative LDS -> global copy of n floats with 16B alignment fixup
__device__ __forceinline__ void copy_f(const float* src, float* dst, int n, int tid) {
    int head = (int)(((16u - ((uintptr_t)dst & 15u)) & 15u) >> 2);
    if (head > n) head = n;
    for (int i = tid; i < head; i += 256) dst[i] = src[i];
    int n4 = (n - head) >> 2;
    const float* s4 = src + head;
    float* d4 = dst + head;
    for (int i = tid; i < n4; i += 256) {
        float4 v = make_float4(s4[4*i], s4[4*i+1], s4[4*i+2], s4[4*i+3]);
        ((float4*)d4)[i] = v;
    }
    int done = head + (n4 << 2);
    for (int i = done + tid; i < n; i += 256) dst[i] = src[i];
}

// ---------------------------------------------------------------------------
// Kernel 2: one thread = 4 consecutive quads; block = 256 threads = 2 rows.
// lower face q: (p, p+W, p+W+1); upper face FH+q: (p, p+W+1, p+1)
// Edge/mask outputs staged in LDS, then copied out with aligned float4s.
// ---------------------------------------------------------------------------
__global__ void __launch_bounds__(256)
faces_kernel(const float* __restrict__ attr_d,
             const float* __restrict__ v_buf,
             float* __restrict__ out_e,
             float* __restrict__ out_m) {
    __shared__ float s_lo[2 * 1533];   // 2 rows x 511 quads x 3 edges
    __shared__ float s_up[2 * 1533];
    __shared__ float s_ml[2 * 511];
    __shared__ float s_mu[2 * 511];

    const int tid = threadIdx.x;
    const int b   = blockIdx.y;
    const int y0  = blockIdx.x * 2;
    const int r   = tid >> 7;        // row within block (0/1)
    const int g   = tid & 127;       // quad-group within row
    const int y   = y0 + r;
    const int x0  = g << 2;

    if (y < HH - 1) {
        const float* zb = attr_d + ((size_t)b * 4 + 3) * NPIX;
        int p0  = y * WW + x0;
        int ext = (g < 127) ? 1 : 0;   // group 127 has only 3 quads

        float4 zt4 = *(const float4*)(zb + p0);
        float zt[5] = {zt4.x, zt4.y, zt4.z, zt4.w, zb[p0 + 3 + ext]};
        float4 zd4 = *(const float4*)(zb + p0 + WW);
        float zd[5] = {zd4.x, zd4.y, zd4.z, zd4.w, zb[p0 + WW + 3 + ext]};

        const float* vb = v_buf + (size_t)b * NPIX * 3;
        const float4* vtp = (const float4*)(vb + (size_t)p0 * 3);          // 16B aligned
        const float4* vdp = (const float4*)(vb + (size_t)(p0 + WW) * 3);
        float4 t0 = vtp[0], t1 = vtp[1], t2 = vtp[2], t3 = vtp[2 + ext];
        float4 u0 = vdp[0], u1 = vdp[1], u2 = vdp[2], u3 = vdp[2 + ext];
        float vt[15] = {t0.x,t0.y,t0.z,t0.w, t1.x,t1.y,t1.z,t1.w,
                        t2.x,t2.y,t2.z,t2.w, t3.x,t3.y,t3.z};
        float vd[15] = {u0.x,u0.y,u0.z,u0.w, u1.x,u1.y,u1.z,u1.w,
                        u2.x,u2.y,u2.z,u2.w, u3.x,u3.y,u3.z};

#pragma unroll
        for (int j = 0; j < 4; ++j) {
            int gx = x0 + j;
            if (gx < WW - 1) {
                float ax = vt[j*3],   ay = vt[j*3+1], az = vt[j*3+2];   // v00
                float bx = vt[j*3+3], by = vt[j*3+4], bz = vt[j*3+5];   // v01
                float cx = vd[j*3],   cy = vd[j*3+1], cz = vd[j*3+2];   // v10
                float dx = vd[j*3+3], dy = vd[j*3+4], dz = vd[j*3+5];   // v11

                float l_a = edge_len3(ax,ay,az, cx,cy,cz);   // lower e0
                float l_b = edge_len3(cx,cy,cz, dx,dy,dz);   // lower e1
                float l_c = edge_len3(dx,dy,dz, ax,ay,az);   // lower e2 / upper e0
                float l_d = edge_len3(dx,dy,dz, bx,by,bz);   // upper e1
                float l_e = edge_len3(bx,by,bz, ax,ay,az);   // upper e2

                bool mlo = (zt[j] > DEPTH_MIN) & (zd[j] > DEPTH_MIN) & (zd[j+1] > DEPTH_MIN) &
                           (l_a < EDGE_MAX) & (l_b < EDGE_MAX) & (l_c < EDGE_MAX);
                bool mup = (zt[j] > DEPTH_MIN) & (zd[j+1] > DEPTH_MIN) & (zt[j+1] > DEPTH_MIN) &
                           (l_c < EDGE_MAX) & (l_d < EDGE_MAX) & (l_e < EDGE_MAX);

                int lb = r * 1533 + gx * 3;
                s_lo[lb]   = l_a;  s_lo[lb+1] = l_b;  s_lo[lb+2] = l_c;
                s_up[lb]   = l_c;  s_up[lb+1] = l_d;  s_up[lb+2] = l_e;
                s_ml[r * 511 + gx] = mlo ? 1.0f : 0.0f;
                s_mu[r * 511 + gx] = mup ? 1.0f : 0.0f;
            }
        }
    }
    __syncthreads();

    int nrows = (y0 + 1 < HH - 1) ? 2 : 1;   // last block covers only row 510
    int n_e = nrows * 1533;
    int n_m = nrows * 511;
    size_t qlo = (size_t)b * NF + (size_t)y0 * 511;
    size_t qup = (size_t)b * NF + FH + (size_t)y0 * 511;
    copy_f(s_lo, out_e + qlo * 3, n_e, tid);
    copy_f(s_up, out_e + qup * 3, n_e, tid);
    copy_f(s_ml, out_m + qlo, n_m, tid);
    copy_f(s_mu, out_m + qup, n_m, tid);
}

extern "C" void kernel_launch(void* const* d_in, const int* in_sizes, int n_in,
                              void* d_out, int out_size, void* d_ws, size_t ws_size,
                              hipStream_t stream) {
    const float* attr_d  = (const float*)d_in[0];
    const float* c2w_int = (const float*)d_in[1];
    const float* c2w_ext = (const float*)d_in[2];

    float* out   = (float*)d_out;
    float* out_v = out;                                  // B*N*3
    float* out_a = out + (size_t)NB * NPIX * 3;          // B*N*3
    float* out_e = out + (size_t)2 * NB * NPIX * 3;      // B*F*3
    float* out_m = out_e + (size_t)NB * NF * 3;          // B*F

    int t1 = NB * NPIX / 4;                              // 524288 threads
    unproject_kernel<<<t1 / 256, 256, 0, stream>>>(attr_d, c2w_int, c2w_ext,
                                                   out_v, out_a);
    dim3 grid2(256, NB);                                 // 256 row-pairs x 8 batches
    faces_kernel<<<grid2, 256, 0, stream>>>(attr_d, out_v, out_e, out_m);
}